// Round 1
// baseline (992.041 us; speedup 1.0000x reference)
//
#include <hip/hip_runtime.h>
#include <math.h>

#define N_SRC   50000
#define N_SAMP  50000
#define N_TOTAL 200000
#define NE      1600000
#define D       256
#define CAP     128   // max edges per row; Poisson(32) tail at 128 ~ 1e-40

// ---- Kernel 1: bucket edges by destination row + owner (last-write-wins) ----
__global__ __launch_bounds__(256) void k_fill(
    const int* __restrict__ adj_row, const int* __restrict__ nodes,
    int* __restrict__ cursor, int* __restrict__ bucket, int* __restrict__ owner)
{
    int idx = blockIdx.x * 256 + threadIdx.x;
    if (idx < NE) {
        int row = adj_row[idx];
        int pos = atomicAdd(&cursor[row], 1);
        if (pos < CAP) bucket[row * CAP + pos] = idx;
    }
    if (idx < N_SAMP) {
        atomicMax(&owner[nodes[idx]], idx);   // owner init -1; max index = numpy last-write-wins
    }
}

// ---- Kernel 2: spmm (one wave per row) + momentum blend, feat -> d_out[0:N_SAMP*D] ----
__global__ __launch_bounds__(256) void k_spmm_blend(
    const float* __restrict__ x, const int* __restrict__ adj_col,
    const float* __restrict__ adj_val, const int* __restrict__ bucket,
    const int* __restrict__ cursor, const int* __restrict__ nodes,
    const float* __restrict__ y_buf, float* __restrict__ feat)
{
    int wave = threadIdx.x >> 6;
    int lane = threadIdx.x & 63;
    int row  = blockIdx.x * 4 + wave;
    if (row >= N_SAMP) return;
    int cnt = cursor[row];
    if (cnt > CAP) cnt = CAP;
    const int* bk = bucket + row * CAP;
    int off = lane * 4;
    float4 acc = make_float4(0.f, 0.f, 0.f, 0.f);
    int j = 0;
    // 2-wide unroll for load ILP (independent gather chains)
    for (; j + 1 < cnt; j += 2) {
        int e0 = bk[j], e1 = bk[j + 1];
        float v0 = adj_val[e0], v1 = adj_val[e1];
        int   c0 = adj_col[e0], c1 = adj_col[e1];
        float4 x0 = *(const float4*)(x + (size_t)c0 * D + off);
        float4 x1 = *(const float4*)(x + (size_t)c1 * D + off);
        acc.x += v0 * x0.x + v1 * x1.x;
        acc.y += v0 * x0.y + v1 * x1.y;
        acc.z += v0 * x0.z + v1 * x1.z;
        acc.w += v0 * x0.w + v1 * x1.w;
    }
    if (j < cnt) {
        int e0 = bk[j];
        float v0 = adj_val[e0];
        int   c0 = adj_col[e0];
        float4 x0 = *(const float4*)(x + (size_t)c0 * D + off);
        acc.x += v0 * x0.x; acc.y += v0 * x0.y;
        acc.z += v0 * x0.z; acc.w += v0 * x0.w;
    }
    int node = nodes[row];
    float4 yv = *(const float4*)(y_buf + (size_t)node * D + off);
    float4 f;
    f.x = 0.9f * yv.x + 0.1f * acc.x;
    f.y = 0.9f * yv.y + 0.1f * acc.y;
    f.z = 0.9f * yv.z + 0.1f * acc.z;
    f.w = 0.9f * yv.w + 0.1f * acc.w;
    *(float4*)(feat + (size_t)row * D + off) = f;
}

// ---- Kernel 3: new_y = owner>=0 ? feat[owner] : 0.9*y_buf (single write/row) ----
__global__ __launch_bounds__(256) void k_newy(
    const float* __restrict__ y_buf, const float* __restrict__ feat,
    const int* __restrict__ owner, float* __restrict__ newy)
{
    int wave = threadIdx.x >> 6;
    int lane = threadIdx.x & 63;
    int row  = blockIdx.x * 4 + wave;
    if (row >= N_TOTAL) return;
    int off = lane * 4;
    int o = owner[row];
    float4 r;
    if (o >= 0) {
        r = *(const float4*)(feat + (size_t)o * D + off);
    } else {
        float4 y = *(const float4*)(y_buf + (size_t)row * D + off);
        r = make_float4(0.9f * y.x, 0.9f * y.y, 0.9f * y.z, 0.9f * y.w);
    }
    *(float4*)(newy + (size_t)row * D + off) = r;
}

// ---- Kernel 4: in-place feat -> elu(feat@W+b) -> per-row norm, fused ----
// Block = 256 threads = 4 waves; 32 rows x 256 cols per block.
// Wave ty owns rows m0..m0+7; lane tx owns cols 4*tx..4*tx+3 -> row
// reductions are pure 64-lane shuffles.
__global__ __launch_bounds__(256) void k_gemm_elu_norm(
    float* __restrict__ io, const float* __restrict__ Wm,
    const float* __restrict__ b, const float* __restrict__ scale,
    const float* __restrict__ offset)
{
    __shared__ float ldsF[32][256];   // feat tile   (32 KB)
    __shared__ float ldsW[32][256];   // W k-tile    (32 KB)
    int t    = threadIdx.x;
    int quad = t >> 6;        // wave id 0..3
    int lane = t & 63;
    int r0   = blockIdx.x * 32;

    // stage feat tile (rows beyond N_SAMP -> 0)
    #pragma unroll
    for (int p = 0; p < 8; ++p) {
        int m  = p * 4 + quad;
        int c4 = lane * 4;
        int r  = r0 + m;
        float4 v = (r < N_SAMP) ? *(const float4*)(io + (size_t)r * D + c4)
                                : make_float4(0.f, 0.f, 0.f, 0.f);
        *(float4*)&ldsF[m][c4] = v;
    }

    int m0 = quad * 8;
    int c0 = lane * 4;
    float acc[8][4];
    #pragma unroll
    for (int mm = 0; mm < 8; ++mm)
        for (int i = 0; i < 4; ++i) acc[mm][i] = 0.f;

    for (int kt = 0; kt < 256; kt += 32) {
        __syncthreads();   // also covers initial ldsF fill at kt==0
        #pragma unroll
        for (int p = 0; p < 8; ++p) {
            int kk = p * 4 + quad;
            int c4 = lane * 4;
            *(float4*)&ldsW[kk][c4] = *(const float4*)(Wm + (size_t)(kt + kk) * D + c4);
        }
        __syncthreads();
        #pragma unroll
        for (int k = 0; k < 32; ++k) {
            float4 wv = *(float4*)&ldsW[k][c0];
            #pragma unroll
            for (int mm = 0; mm < 8; ++mm) {
                float fm = ldsF[m0 + mm][kt + k];   // wave-uniform broadcast read
                acc[mm][0] += fm * wv.x;
                acc[mm][1] += fm * wv.y;
                acc[mm][2] += fm * wv.z;
                acc[mm][3] += fm * wv.w;
            }
        }
    }

    float4 bv = *(const float4*)(b + c0);
    float4 sv = *(const float4*)(scale + c0);
    float4 ov = *(const float4*)(offset + c0);

    #pragma unroll
    for (int mm = 0; mm < 8; ++mm) {
        float o0 = acc[mm][0] + bv.x;
        float o1 = acc[mm][1] + bv.y;
        float o2 = acc[mm][2] + bv.z;
        float o3 = acc[mm][3] + bv.w;
        o0 = o0 > 0.f ? o0 : expf(o0) - 1.f;
        o1 = o1 > 0.f ? o1 : expf(o1) - 1.f;
        o2 = o2 > 0.f ? o2 : expf(o2) - 1.f;
        o3 = o3 > 0.f ? o3 : expf(o3) - 1.f;
        float s = o0 + o1 + o2 + o3;
        float q = o0 * o0 + o1 * o1 + o2 * o2 + o3 * o3;
        #pragma unroll
        for (int d2 = 1; d2 < 64; d2 <<= 1) {
            s += __shfl_xor(s, d2, 64);
            q += __shfl_xor(q, d2, 64);
        }
        float mean = s * (1.0f / 256.0f);
        float var  = q * (1.0f / 256.0f) - mean * mean + 1e-9f;
        float rstd = rsqrtf(var);
        int r = r0 + m0 + mm;
        if (r < N_SAMP) {
            float4 res;
            res.x = (o0 - mean) * sv.x * rstd + ov.x;
            res.y = (o1 - mean) * sv.y * rstd + ov.y;
            res.z = (o2 - mean) * sv.z * rstd + ov.z;
            res.w = (o3 - mean) * sv.w * rstd + ov.w;
            *(float4*)(io + (size_t)r * D + c0) = res;
        }
    }
}

extern "C" void kernel_launch(void* const* d_in, const int* in_sizes, int n_in,
                              void* d_out, int out_size, void* d_ws, size_t ws_size,
                              hipStream_t stream) {
    const float* x       = (const float*)d_in[0];
    const int*   adj_row = (const int*)  d_in[1];
    const int*   adj_col = (const int*)  d_in[2];
    const float* adj_val = (const float*)d_in[3];
    const int*   nodes   = (const int*)  d_in[4];
    const float* y_buf   = (const float*)d_in[5];
    const float* Wm      = (const float*)d_in[6];
    const float* b       = (const float*)d_in[7];
    const float* scale   = (const float*)d_in[8];
    const float* offset  = (const float*)d_in[9];

    float* out  = (float*)d_out;                  // [N_SAMP, D] (feat staged here first)
    float* newy = out + (size_t)N_SAMP * D;       // [N_TOTAL, D]

    char* ws     = (char*)d_ws;
    int*  cursor = (int*)ws;                      // N_SAMP ints   (200 KB)
    int*  owner  = (int*)(ws + 256 * 1024);       // N_TOTAL ints  (800 KB)
    int*  bucket = (int*)(ws + 1280 * 1024);      // N_SAMP*CAP ints (25.6 MB)

    hipMemsetAsync(cursor, 0,    N_SAMP  * sizeof(int), stream);
    hipMemsetAsync(owner,  0xFF, N_TOTAL * sizeof(int), stream);  // owner = -1

    k_fill<<<(NE + 255) / 256, 256, 0, stream>>>(adj_row, nodes, cursor, bucket, owner);
    k_spmm_blend<<<(N_SAMP + 3) / 4, 256, 0, stream>>>(
        x, adj_col, adj_val, bucket, cursor, nodes, y_buf, out);
    k_newy<<<(N_TOTAL + 3) / 4, 256, 0, stream>>>(y_buf, out, owner, newy);
    k_gemm_elu_norm<<<(N_SAMP + 31) / 32, 256, 0, stream>>>(out, Wm, b, scale, offset);
}